// Round 1
// baseline (1704.568 us; speedup 1.0000x reference)
//
#include <hip/hip_runtime.h>

#define HW 16384
#define PIf 3.14159265358979323846f

// ---------- bf16 raw helpers ----------
__device__ __forceinline__ float bf2f(unsigned short b) {
    return __uint_as_float(((unsigned)b) << 16);
}
__device__ __forceinline__ unsigned short f2bf(float f) {
    unsigned u = __float_as_uint(f);
    u += 0x7fffu + ((u >> 16) & 1u);   // RNE
    return (unsigned short)(u >> 16);
}
__device__ __forceinline__ int brev7(int v) { return (int)(__brev((unsigned)v) >> 25); }

// ---------- in-place 2D DIF FFT, 128x128, LDS ----------
// Input natural order; output X[u][v] located at s[brev7(u)][brev7(v)].
__device__ __forceinline__ void fft2d_128(float (*sre)[129], float (*sim)[129],
                                          const float* twr, const float* twi, int tid) {
    // rows (FFT along 2nd index)
    for (int s = 0; s < 7; ++s) {
        int half = 64 >> s;
        __syncthreads();
        #pragma unroll 4
        for (int it = 0; it < 32; ++it) {
            int idx = (it << 8) + tid;
            int row = idx & 127;
            int j   = idx >> 7;              // 0..63
            int k   = j & (half - 1);
            int g   = j >> (6 - s);
            int i0  = (g << (7 - s)) + k;
            int i1  = i0 + half;
            float tr = twr[k << s], ti = twi[k << s];
            float ar = sre[row][i0], ai = sim[row][i0];
            float br = sre[row][i1], bi = sim[row][i1];
            sre[row][i0] = ar + br;  sim[row][i0] = ai + bi;
            float dr = ar - br, di = ai - bi;
            sre[row][i1] = dr * tr - di * ti;
            sim[row][i1] = dr * ti + di * tr;
        }
    }
    // cols (FFT along 1st index)
    for (int s = 0; s < 7; ++s) {
        int half = 64 >> s;
        __syncthreads();
        #pragma unroll 4
        for (int it = 0; it < 32; ++it) {
            int idx = (it << 8) + tid;
            int col = idx & 127;
            int j   = idx >> 7;
            int k   = j & (half - 1);
            int g   = j >> (6 - s);
            int i0  = (g << (7 - s)) + k;
            int i1  = i0 + half;
            float tr = twr[k << s], ti = twi[k << s];
            float ar = sre[i0][col], ai = sim[i0][col];
            float br = sre[i1][col], bi = sim[i1][col];
            sre[i0][col] = ar + br;  sim[i0][col] = ai + bi;
            float dr = ar - br, di = ai - bi;
            sre[i1][col] = dr * tr - di * ti;
            sim[i1][col] = dr * ti + di * tr;
        }
    }
    __syncthreads();
}

// ---------- Stage A: forward FFT + fftshift + central-mag accumulation ----------
__global__ __launch_bounds__(256) void fft_fwd(const float* __restrict__ x,
                                               unsigned short* __restrict__ xfRe,
                                               unsigned short* __restrict__ xfIm,
                                               float* __restrict__ magc) {
    __shared__ float sre[128][129];
    __shared__ float sim[128][129];
    __shared__ float twr[64], twi[64];
    int img = blockIdx.x;                 // b*256 + c
    int tid = threadIdx.x;
    const float* xi = x + (size_t)img * HW;
    for (int idx = tid; idx < HW; idx += 256) {
        sre[idx >> 7][idx & 127] = xi[idx];
        sim[idx >> 7][idx & 127] = 0.f;
    }
    if (tid < 64) {
        float s, c;
        sincosf(-PIf * (float)tid / 64.0f, &s, &c);  // e^{-2*pi*i*k/128}
        twr[tid] = c; twi[tid] = s;
    }
    fft2d_128(sre, sim, twr, twi, tid);

    // write fftshift'd, ortho-normalized (1/128), bf16-packed
    unsigned int* oRe = (unsigned int*)(xfRe + ((size_t)img << 14));
    unsigned int* oIm = (unsigned int*)(xfIm + ((size_t)img << 14));
    for (int idx2 = tid; idx2 < 8192; idx2 += 256) {
        int p = idx2 >> 6, qp = idx2 & 63, q = qp * 2;
        int u  = brev7((p + 64) & 127);
        int v0 = brev7((q + 64) & 127);
        int v1 = brev7((q + 65) & 127);
        const float sc = 1.0f / 128.0f;
        unsigned int re = (unsigned)f2bf(sre[u][v0] * sc) | ((unsigned)f2bf(sre[u][v1] * sc) << 16);
        unsigned int im = (unsigned)f2bf(sim[u][v0] * sc) | ((unsigned)f2bf(sim[u][v1] * sc) << 16);
        oRe[p * 64 + qp] = re;
        oIm[p * 64 + qp] = im;
    }
    // central 7x7 |xf| accumulation (fp32, pre-bf16)
    if (tid < 49) {
        int p = 61 + tid / 7, q = 61 + tid % 7;
        int u = brev7((p + 64) & 127);
        int v = brev7((q + 64) & 127);
        float re = sre[u][v], im = sim[u][v];
        float mag = sqrtf(re * re + im * im) * (1.0f / 128.0f);
        atomicAdd(&magc[(img >> 8) * 49 + tid], mag);
    }
}

// ---------- Stage B: tiny MLP + anisotropic kernel build ----------
__global__ __launch_bounds__(256) void mlp_kern(const float* __restrict__ magc,
                                                const float* __restrict__ w1,
                                                const float* __restrict__ b1,
                                                const float* __restrict__ w2,
                                                const float* __restrict__ b2,
                                                float* __restrict__ kern) {
    __shared__ float hid[8][32];
    __shared__ float par[8][3];
    __shared__ float kun[8][49];
    __shared__ float ksum[8];
    int tid = threadIdx.x;
    {   // hid = relu(center @ w1 + b1), center = magc/256
        int b = tid >> 5, n = tid & 31;
        float acc = b1[n];
        for (int i = 0; i < 49; ++i)
            acc = fmaf(magc[b * 49 + i] * (1.0f / 256.0f), w1[i * 32 + n], acc);
        hid[b][n] = fmaxf(acc, 0.f);
    }
    __syncthreads();
    if (tid < 24) {
        int b = tid / 3, j = tid % 3;
        float acc = b2[j];
        for (int n = 0; n < 32; ++n) acc = fmaf(hid[b][n], w2[n * 3 + j], acc);
        par[b][j] = acc;
    }
    __syncthreads();
    for (int idx = tid; idx < 392; idx += 256) {
        int b = idx / 49, ij = idx % 49;
        int i = ij / 7, j2 = ij % 7;
        float p0 = par[b][0], p1 = par[b][1], p2 = par[b][2];
        float theta = atan2f(p0, p1) * 0.5f + PIf * 0.5f;
        float lam1 = expf(p2);
        float lam2 = 1.0f / (lam1 + 1e-8f);
        float yy = (float)(i - 3), xx = (float)(j2 - 3);
        float ct, st;
        sincosf(theta, &st, &ct);
        float xr =  xx * ct + yy * st;
        float yr = -xx * st + yy * ct;
        kun[b][ij] = expf(-(xr * xr / (2.f * lam1 * lam1) + yr * yr / (2.f * lam2 * lam2)));
    }
    __syncthreads();
    if (tid < 8) {
        float s = 0.f;
        for (int t = 0; t < 49; ++t) s += kun[tid][t];
        ksum[tid] = s + 1e-8f;
    }
    __syncthreads();
    for (int idx = tid; idx < 392; idx += 256)
        kern[idx] = kun[idx / 49][idx % 49] / ksum[idx / 49];
}

// ---------- Stage C: channel mixing (mixed = wr x xf), fp32 tiled GEMM ----------
// out[b,part,o,hw] = sum_c wr[o,c] * xf_part[b,c,hw]; M=256(o), N=16384(hw), K=256(c)
__global__ __launch_bounds__(256) void gemm_mix(const unsigned short* __restrict__ xfRe,
                                                const unsigned short* __restrict__ xfIm,
                                                const float* __restrict__ wr,
                                                unsigned short* __restrict__ mixRe,
                                                unsigned short* __restrict__ mixIm) {
    __shared__ float aT[64][128];     // [k][hw]
    __shared__ float wT[64][65];      // [k][o]
    int tid = threadIdx.x;
    int b = blockIdx.z >> 1, part = blockIdx.z & 1;
    const unsigned short* src = part ? xfIm : xfRe;
    unsigned short* dst = part ? mixIm : mixRe;
    int oBase   = blockIdx.y * 64;
    int pixBase = blockIdx.x * 128;
    float acc[8][4];
    #pragma unroll
    for (int i = 0; i < 8; ++i)
        #pragma unroll
        for (int j = 0; j < 4; ++j) acc[i][j] = 0.f;
    int tx = tid & 31, ty = tid >> 5;

    for (int kb = 0; kb < 4; ++kb) {
        int kBase = kb * 64;
        __syncthreads();
        #pragma unroll
        for (int i = 0; i < 16; ++i) {      // A tile: 8192 bf16 = 4096 uints
            int idx = tid + i * 256;
            int k = idx >> 6, hp = idx & 63;
            unsigned int v = *(const unsigned int*)
                (src + (((size_t)(b * 256 + kBase + k)) << 14) + pixBase + hp * 2);
            aT[k][hp * 2]     = bf2f((unsigned short)(v & 0xffff));
            aT[k][hp * 2 + 1] = bf2f((unsigned short)(v >> 16));
        }
        #pragma unroll
        for (int i = 0; i < 16; ++i) {      // wr tile (transposed into [k][o])
            int idx = tid + i * 256;
            int o = idx >> 6, k = idx & 63;
            wT[k][o] = wr[(oBase + o) * 256 + kBase + k];
        }
        __syncthreads();
        #pragma unroll 2
        for (int k = 0; k < 64; ++k) {
            float4 av = *(const float4*)&aT[k][tx * 4];
            float a4[4] = {av.x, av.y, av.z, av.w};
            float wv[8];
            #pragma unroll
            for (int oo = 0; oo < 8; ++oo) wv[oo] = wT[k][ty * 8 + oo];
            #pragma unroll
            for (int oo = 0; oo < 8; ++oo)
                #pragma unroll
                for (int ww = 0; ww < 4; ++ww)
                    acc[oo][ww] = fmaf(wv[oo], a4[ww], acc[oo][ww]);
        }
    }
    #pragma unroll
    for (int oo = 0; oo < 8; ++oo) {
        int o = oBase + ty * 8 + oo;
        unsigned short* dp = dst + (((size_t)(b * 256 + o)) << 14) + pixBase + tx * 4;
        unsigned int p0 = (unsigned)f2bf(acc[oo][0]) | ((unsigned)f2bf(acc[oo][1]) << 16);
        unsigned int p1 = (unsigned)f2bf(acc[oo][2]) | ((unsigned)f2bf(acc[oo][3]) << 16);
        *(unsigned int*)(dp)     = p0;
        *(unsigned int*)(dp + 2) = p1;
    }
}

// ---------- Stage D: 7x7 zero-padded conv (per-batch kernel) ----------
__global__ __launch_bounds__(256) void conv7(const unsigned short* __restrict__ mixRe,
                                             const unsigned short* __restrict__ mixIm,
                                             const float* __restrict__ kern,
                                             unsigned short* __restrict__ outRe,
                                             unsigned short* __restrict__ outIm) {
    __shared__ float tile[38][40];
    __shared__ float kk[49];
    int b = blockIdx.z;
    int plane = blockIdx.y;                  // 0..511: part = >>8, o = &255
    int part = plane >> 8;
    size_t pbase = ((size_t)(b * 256 + (plane & 255))) << 14;
    const unsigned short* src = (part ? mixIm : mixRe) + pbase;
    unsigned short* dst = (part ? outIm : outRe) + pbase;
    int ty = (blockIdx.x >> 2) * 32, tx = (blockIdx.x & 3) * 32;
    int tid = threadIdx.x;
    if (tid < 49) kk[tid] = kern[b * 49 + tid];
    for (int idx = tid; idx < 38 * 38; idx += 256) {
        int i = idx / 38, j = idx % 38;
        int r = ty + i - 3, c = tx + j - 3;
        float v = 0.f;
        if ((unsigned)r < 128u && (unsigned)c < 128u) v = bf2f(src[r * 128 + c]);
        tile[i][j] = v;
    }
    __syncthreads();
    #pragma unroll
    for (int rep = 0; rep < 4; ++rep) {
        int idx = tid + rep * 256;
        int yy = idx >> 5, xx = idx & 31;
        float acc = 0.f;
        #pragma unroll
        for (int dy = 0; dy < 7; ++dy)
            #pragma unroll
            for (int dx = 0; dx < 7; ++dx)
                acc = fmaf(tile[yy + dy][xx + dx], kk[dy * 7 + dx], acc);
        dst[(ty + yy) * 128 + tx + xx] = f2bf(acc);
    }
}

// ---------- Stage E: ifftshift + inverse FFT (conj trick) + residual add ----------
__global__ __launch_bounds__(256) void ifft_add(const unsigned short* __restrict__ convRe,
                                                const unsigned short* __restrict__ convIm,
                                                const float* __restrict__ x,
                                                float* __restrict__ out) {
    __shared__ float sre[128][129];
    __shared__ float sim[128][129];
    __shared__ float twr[64], twi[64];
    int img = blockIdx.x;                 // b*256 + o
    int tid = threadIdx.x;
    const unsigned short* cr = convRe + ((size_t)img << 14);
    const unsigned short* ci = convIm + ((size_t)img << 14);
    for (int idx2 = tid; idx2 < 8192; idx2 += 256) {
        int u = idx2 >> 6, vp = idx2 & 63, v = vp * 2;
        int p = (u + 64) & 127, q = (v + 64) & 127;   // ifftshift gather (q even, pair contiguous)
        unsigned int re = *(const unsigned int*)(cr + p * 128 + q);
        unsigned int im = *(const unsigned int*)(ci + p * 128 + q);
        sre[u][v]     =  bf2f((unsigned short)(re & 0xffff));
        sre[u][v + 1] =  bf2f((unsigned short)(re >> 16));
        sim[u][v]     = -bf2f((unsigned short)(im & 0xffff));  // conj
        sim[u][v + 1] = -bf2f((unsigned short)(im >> 16));
    }
    if (tid < 64) {
        float s, c;
        sincosf(-PIf * (float)tid / 64.0f, &s, &c);
        twr[tid] = c; twi[tid] = s;
    }
    fft2d_128(sre, sim, twr, twi, tid);

    const float* xi = x + (size_t)img * HW;
    float* oo = out + (size_t)img * HW;
    for (int idx2 = tid; idx2 < 8192; idx2 += 256) {
        int y = idx2 >> 6, xp = (idx2 & 63) * 2;
        int ry = brev7(y);
        float r0 = sre[ry][brev7(xp)]     * (1.0f / 128.0f);
        float r1 = sre[ry][brev7(xp + 1)] * (1.0f / 128.0f);
        float2 xv = *(const float2*)(xi + y * 128 + xp);
        float2 ov; ov.x = r0 + xv.x; ov.y = r1 + xv.y;
        *(float2*)(oo + y * 128 + xp) = ov;
    }
}

extern "C" void kernel_launch(void* const* d_in, const int* in_sizes, int n_in,
                              void* d_out, int out_size, void* d_ws, size_t ws_size,
                              hipStream_t stream) {
    const float* x  = (const float*)d_in[0];
    const float* w1 = (const float*)d_in[1];
    const float* b1 = (const float*)d_in[2];
    const float* w2 = (const float*)d_in[3];
    const float* b2 = (const float*)d_in[4];
    const float* wr = (const float*)d_in[5];

    char* ws = (char*)d_ws;
    unsigned short* xfRe  = (unsigned short*)ws;                    // 64 MiB
    unsigned short* xfIm  = xfRe + 33554432;                        // 64 MiB
    unsigned short* mixRe = (unsigned short*)(ws + 134217728);      // 64 MiB
    unsigned short* mixIm = mixRe + 33554432;                       // 64 MiB
    float* magc = (float*)(ws + 268435456);                         // 392 f
    float* kern = (float*)(ws + 268435456 + 2048);                  // 392 f

    hipMemsetAsync(magc, 0, 392 * sizeof(float), stream);
    fft_fwd<<<2048, 256, 0, stream>>>(x, xfRe, xfIm, magc);
    mlp_kern<<<1, 256, 0, stream>>>(magc, w1, b1, w2, b2, kern);
    gemm_mix<<<dim3(128, 4, 16), 256, 0, stream>>>(xfRe, xfIm, wr, mixRe, mixIm);
    // conv output reuses the xf buffers (gemm has consumed them)
    conv7<<<dim3(16, 512, 8), 256, 0, stream>>>(mixRe, mixIm, kern, xfRe, xfIm);
    ifft_add<<<2048, 256, 0, stream>>>(xfRe, xfIm, x, (float*)d_out);
}

// Round 2
// 1052.852 us; speedup vs baseline: 1.6190x; 1.6190x over previous
//
#include <hip/hip_runtime.h>

#define HW 16384
#define PIf 3.14159265358979323846f
typedef unsigned short ushortt;
typedef unsigned int uint32;
typedef __attribute__((ext_vector_type(8))) short short8;
typedef __attribute__((ext_vector_type(4))) float f32x4;

// ---------- bf16 raw helpers ----------
__device__ __forceinline__ float bf2f(ushortt b) {
    return __uint_as_float(((unsigned)b) << 16);
}
__device__ __forceinline__ ushortt f2bf(float f) {
    unsigned u = __float_as_uint(f);
    u += 0x7fffu + ((u >> 16) & 1u);   // RNE
    return (ushortt)(u >> 16);
}
__device__ __forceinline__ int brev7(int v) { return (int)(__brev((unsigned)v) >> 25); }

// ---------- in-place 2D DIF FFT, 128x128, LDS, 512 threads ----------
__device__ __forceinline__ void fft2d_128(float (*sre)[129], float (*sim)[129],
                                          const float* twr, const float* twi, int tid) {
    for (int s = 0; s < 7; ++s) {
        int half = 64 >> s;
        __syncthreads();
        #pragma unroll 4
        for (int it = 0; it < 16; ++it) {
            int idx = (it << 9) + tid;
            int row = idx & 127;
            int j   = idx >> 7;
            int k   = j & (half - 1);
            int g   = j >> (6 - s);
            int i0  = (g << (7 - s)) + k;
            int i1  = i0 + half;
            float tr = twr[k << s], ti = twi[k << s];
            float ar = sre[row][i0], ai = sim[row][i0];
            float br = sre[row][i1], bi = sim[row][i1];
            sre[row][i0] = ar + br;  sim[row][i0] = ai + bi;
            float dr = ar - br, di = ai - bi;
            sre[row][i1] = dr * tr - di * ti;
            sim[row][i1] = dr * ti + di * tr;
        }
    }
    for (int s = 0; s < 7; ++s) {
        int half = 64 >> s;
        __syncthreads();
        #pragma unroll 4
        for (int it = 0; it < 16; ++it) {
            int idx = (it << 9) + tid;
            int col = idx & 127;
            int j   = idx >> 7;
            int k   = j & (half - 1);
            int g   = j >> (6 - s);
            int i0  = (g << (7 - s)) + k;
            int i1  = i0 + half;
            float tr = twr[k << s], ti = twi[k << s];
            float ar = sre[i0][col], ai = sim[i0][col];
            float br = sre[i1][col], bi = sim[i1][col];
            sre[i0][col] = ar + br;  sim[i0][col] = ai + bi;
            float dr = ar - br, di = ai - bi;
            sre[i1][col] = dr * tr - di * ti;
            sim[i1][col] = dr * ti + di * tr;
        }
    }
    __syncthreads();
}

// ---------- Stage A: forward FFT + fftshift + central-mag accumulation ----------
__global__ __launch_bounds__(512) void fft_fwd(const float* __restrict__ x,
                                               ushortt* __restrict__ xfRe,
                                               ushortt* __restrict__ xfIm,
                                               float* __restrict__ magc) {
    __shared__ float sre[128][129];
    __shared__ float sim[128][129];
    __shared__ float twr[64], twi[64];
    int img = blockIdx.x;
    int tid = threadIdx.x;
    const float* xi = x + (size_t)img * HW;
    for (int idx = tid; idx < HW; idx += 512) {
        sre[idx >> 7][idx & 127] = xi[idx];
        sim[idx >> 7][idx & 127] = 0.f;
    }
    if (tid < 64) {
        float s, c;
        sincosf(-PIf * (float)tid / 64.0f, &s, &c);
        twr[tid] = c; twi[tid] = s;
    }
    fft2d_128(sre, sim, twr, twi, tid);

    uint32* oRe = (uint32*)(xfRe + ((size_t)img << 14));
    uint32* oIm = (uint32*)(xfIm + ((size_t)img << 14));
    for (int idx2 = tid; idx2 < 8192; idx2 += 512) {
        int p = idx2 >> 6, qp = idx2 & 63, q = qp * 2;
        int u  = brev7((p + 64) & 127);
        int v0 = brev7((q + 64) & 127);
        int v1 = brev7((q + 65) & 127);
        const float sc = 1.0f / 128.0f;
        uint32 re = (uint32)f2bf(sre[u][v0] * sc) | ((uint32)f2bf(sre[u][v1] * sc) << 16);
        uint32 im = (uint32)f2bf(sim[u][v0] * sc) | ((uint32)f2bf(sim[u][v1] * sc) << 16);
        oRe[p * 64 + qp] = re;
        oIm[p * 64 + qp] = im;
    }
    if (tid < 49) {
        int p = 61 + tid / 7, q = 61 + tid % 7;
        int u = brev7((p + 64) & 127);
        int v = brev7((q + 64) & 127);
        float re = sre[u][v], im = sim[u][v];
        float mag = sqrtf(re * re + im * im) * (1.0f / 128.0f);
        atomicAdd(&magc[(img >> 8) * 49 + tid], mag);
    }
}

// ---------- Stage B: tiny MLP + anisotropic kernel build ----------
__global__ __launch_bounds__(256) void mlp_kern(const float* __restrict__ magc,
                                                const float* __restrict__ w1,
                                                const float* __restrict__ b1,
                                                const float* __restrict__ w2,
                                                const float* __restrict__ b2,
                                                float* __restrict__ kern) {
    __shared__ float hid[8][32];
    __shared__ float par[8][3];
    __shared__ float kun[8][49];
    __shared__ float ksum[8];
    int tid = threadIdx.x;
    {
        int b = tid >> 5, n = tid & 31;
        float acc = b1[n];
        for (int i = 0; i < 49; ++i)
            acc = fmaf(magc[b * 49 + i] * (1.0f / 256.0f), w1[i * 32 + n], acc);
        hid[b][n] = fmaxf(acc, 0.f);
    }
    __syncthreads();
    if (tid < 24) {
        int b = tid / 3, j = tid % 3;
        float acc = b2[j];
        for (int n = 0; n < 32; ++n) acc = fmaf(hid[b][n], w2[n * 3 + j], acc);
        par[b][j] = acc;
    }
    __syncthreads();
    for (int idx = tid; idx < 392; idx += 256) {
        int b = idx / 49, ij = idx % 49;
        int i = ij / 7, j2 = ij % 7;
        float p0 = par[b][0], p1 = par[b][1], p2 = par[b][2];
        float theta = atan2f(p0, p1) * 0.5f + PIf * 0.5f;
        float lam1 = expf(p2);
        float lam2 = 1.0f / (lam1 + 1e-8f);
        float yy = (float)(i - 3), xx = (float)(j2 - 3);
        float ct, st;
        sincosf(theta, &st, &ct);
        float xr =  xx * ct + yy * st;
        float yr = -xx * st + yy * ct;
        kun[b][ij] = expf(-(xr * xr / (2.f * lam1 * lam1) + yr * yr / (2.f * lam2 * lam2)));
    }
    __syncthreads();
    if (tid < 8) {
        float s = 0.f;
        for (int t = 0; t < 49; ++t) s += kun[tid][t];
        ksum[tid] = s + 1e-8f;
    }
    __syncthreads();
    for (int idx = tid; idx < 392; idx += 256)
        kern[idx] = kun[idx / 49][idx % 49] / ksum[idx / 49];
}

// ---------- Stage C0: transpose xf[c][pix] -> xfT[pix][c] ----------
__global__ __launch_bounds__(256) void xpose(const ushortt* __restrict__ xfRe,
                                             const ushortt* __restrict__ xfIm,
                                             ushortt* __restrict__ xfTRe,
                                             ushortt* __restrict__ xfTIm) {
    __shared__ ushortt T[64 * 65];
    int b = blockIdx.z >> 1, arr = blockIdx.z & 1;
    const ushortt* src = (arr ? xfIm : xfRe) + (size_t)b * (256 * HW);
    ushortt* dst = (arr ? xfTIm : xfTRe) + (size_t)b * (HW * 256);
    int pixBase = blockIdx.x * 64, cBase = blockIdx.y * 64;
    int tid = threadIdx.x;
    #pragma unroll
    for (int i = 0; i < 16; ++i) {
        int idx = tid + i * 256; int c = idx >> 6, p = idx & 63;
        T[c * 65 + p] = src[(size_t)(cBase + c) * HW + pixBase + p];
    }
    __syncthreads();
    #pragma unroll
    for (int i = 0; i < 16; ++i) {
        int idx = tid + i * 256; int p = idx >> 6, c = idx & 63;
        dst[(size_t)(pixBase + p) * 256 + cBase + c] = T[c * 65 + p];
    }
}

// ---------- Stage C: channel mixing via bf16 MFMA ----------
// D[o][pix] = sum_c wr[o][c] * xfT[pix][c];  A=wr (M=o), B=xfT (N=pix), K=c=256.
// Block: 128(o) x 128(pix), 4 waves 2x2, wave = 64x64 = 4x4 frags of 16x16x32.
__global__ __launch_bounds__(256) void gemm_mix(const ushortt* __restrict__ xfTRe,
                                                const ushortt* __restrict__ xfTIm,
                                                const float* __restrict__ wr,
                                                ushortt* __restrict__ mixRe,
                                                ushortt* __restrict__ mixIm) {
    __shared__ ushortt lA[2][5120];   // [o=128][k=32] stride 40 ushorts (pad: 2-way free)
    __shared__ ushortt lB[2][5120];   // [pix=128][k=32] stride 40
    int tid = threadIdx.x;
    int lane = tid & 63, wave = tid >> 6;
    int wm = wave >> 1, wn = wave & 1;
    int l15 = lane & 15, q4 = lane >> 4;
    int b = blockIdx.z >> 1, part = blockIdx.z & 1;
    const ushortt* X = (part ? xfTIm : xfTRe) + (size_t)b * (HW * 256)
                       + (size_t)blockIdx.x * (128 * 256);
    ushortt* Dst = (part ? mixIm : mixRe) + (size_t)b * (256 * HW)
                   + (size_t)(blockIdx.y * 128) * HW + blockIdx.x * 128;
    const float* W = wr + (blockIdx.y * 128) * 256;

    int srow = tid >> 1, shalf = tid & 1;
    const float*   wRow = W + srow * 256 + shalf * 16;
    const ushortt* xRow = X + srow * 256 + shalf * 16;
    int ldsOff = srow * 40 + shalf * 16;

    float4 wreg[4];
    uint4  xreg[2];
    #pragma unroll
    for (int i = 0; i < 4; ++i) wreg[i] = *(const float4*)(wRow + i * 4);
    #pragma unroll
    for (int i = 0; i < 2; ++i) xreg[i] = *(const uint4*)(xRow + i * 8);

    f32x4 acc[4][4];
    #pragma unroll
    for (int i = 0; i < 4; ++i)
        #pragma unroll
        for (int j = 0; j < 4; ++j)
            #pragma unroll
            for (int k = 0; k < 4; ++k) acc[i][j][k] = 0.f;

    int abase = (wm * 64 + l15) * 40 + q4 * 8;
    int bbase = (wn * 64 + l15) * 40 + q4 * 8;

    for (int kb = 0; kb < 8; ++kb) {
        int bufc = kb & 1;
        // pack A (fp32 -> bf16) and write both tiles
        float ff[16] = {wreg[0].x, wreg[0].y, wreg[0].z, wreg[0].w,
                        wreg[1].x, wreg[1].y, wreg[1].z, wreg[1].w,
                        wreg[2].x, wreg[2].y, wreg[2].z, wreg[2].w,
                        wreg[3].x, wreg[3].y, wreg[3].z, wreg[3].w};
        uint32 p[8];
        #pragma unroll
        for (int j = 0; j < 8; ++j)
            p[j] = (uint32)f2bf(ff[2 * j]) | ((uint32)f2bf(ff[2 * j + 1]) << 16);
        *(uint4*)&lA[bufc][ldsOff]     = make_uint4(p[0], p[1], p[2], p[3]);
        *(uint4*)&lA[bufc][ldsOff + 8] = make_uint4(p[4], p[5], p[6], p[7]);
        *(uint4*)&lB[bufc][ldsOff]     = xreg[0];
        *(uint4*)&lB[bufc][ldsOff + 8] = xreg[1];
        __syncthreads();
        if (kb < 7) {
            const float*   wN = wRow + (kb + 1) * 32;
            const ushortt* xN = xRow + (kb + 1) * 32;
            #pragma unroll
            for (int i = 0; i < 4; ++i) wreg[i] = *(const float4*)(wN + i * 4);
            #pragma unroll
            for (int i = 0; i < 2; ++i) xreg[i] = *(const uint4*)(xN + i * 8);
        }
        short8 af[4], bf[4];
        #pragma unroll
        for (int f = 0; f < 4; ++f) af[f] = *(const short8*)&lA[bufc][abase + f * 640];
        #pragma unroll
        for (int f = 0; f < 4; ++f) bf[f] = *(const short8*)&lB[bufc][bbase + f * 640];
        #pragma unroll
        for (int fi = 0; fi < 4; ++fi)
            #pragma unroll
            for (int fj = 0; fj < 4; ++fj)
                acc[fi][fj] = __builtin_amdgcn_mfma_f32_16x16x32_bf16(
                    af[fi], bf[fj], acc[fi][fj], 0, 0, 0);
    }
    // epilogue: D row m = o (q4*4+r), col n = pix (l15)
    #pragma unroll
    for (int fi = 0; fi < 4; ++fi) {
        #pragma unroll
        for (int r = 0; r < 4; ++r) {
            int o_l = wm * 64 + fi * 16 + q4 * 4 + r;
            ushortt* dp = Dst + (size_t)o_l * HW + wn * 64 + l15;
            #pragma unroll
            for (int fj = 0; fj < 4; ++fj)
                dp[fj * 16] = f2bf(acc[fi][fj][r]);
        }
    }
}

// ---------- Stage D: 7x7 zero-padded conv, register-blocked 2x8/thread ----------
__global__ __launch_bounds__(256) void conv7(const ushortt* __restrict__ mixRe,
                                             const ushortt* __restrict__ mixIm,
                                             const float* __restrict__ kern,
                                             ushortt* __restrict__ outRe,
                                             ushortt* __restrict__ outIm) {
    __shared__ float tile[70 * 73];   // stride 73 (odd -> ~2-way banks)
    int b = blockIdx.z;
    int plane = blockIdx.y;
    int part = plane >> 8;
    size_t pbase = ((size_t)(b * 256 + (plane & 255))) << 14;
    const ushortt* src = (part ? mixIm : mixRe) + pbase;
    ushortt* dst = (part ? outIm : outRe) + pbase;
    int ty = (blockIdx.x >> 1) * 64, tx = (blockIdx.x & 1) * 64;
    int tid = threadIdx.x;
    float kv[49];
    #pragma unroll
    for (int i = 0; i < 49; ++i) kv[i] = kern[b * 49 + i];   // b uniform -> scalar loads
    for (int idx = tid; idx < 4900; idx += 256) {
        int i = idx / 70, j = idx - i * 70;
        int r = ty + i - 3, c = tx + j - 3;
        float v = 0.f;
        if ((unsigned)r < 128u && (unsigned)c < 128u) v = bf2f(src[r * 128 + c]);
        tile[i * 73 + j] = v;
    }
    __syncthreads();
    int ox = (tid & 7) * 8, oy = (tid >> 3) * 2;
    float a0[8], a1[8];
    #pragma unroll
    for (int j = 0; j < 8; ++j) { a0[j] = 0.f; a1[j] = 0.f; }
    #pragma unroll
    for (int dyy = 0; dyy < 8; ++dyy) {
        float row[14];
        #pragma unroll
        for (int j = 0; j < 14; ++j) row[j] = tile[(oy + dyy) * 73 + ox + j];
        if (dyy < 7) {
            #pragma unroll
            for (int dx = 0; dx < 7; ++dx) {
                float k = kv[dyy * 7 + dx];
                #pragma unroll
                for (int j = 0; j < 8; ++j) a0[j] = fmaf(row[dx + j], k, a0[j]);
            }
        }
        if (dyy >= 1) {
            #pragma unroll
            for (int dx = 0; dx < 7; ++dx) {
                float k = kv[(dyy - 1) * 7 + dx];
                #pragma unroll
                for (int j = 0; j < 8; ++j) a1[j] = fmaf(row[dx + j], k, a1[j]);
            }
        }
    }
    uint32 s0[4], s1[4];
    #pragma unroll
    for (int j = 0; j < 4; ++j) {
        s0[j] = (uint32)f2bf(a0[2 * j]) | ((uint32)f2bf(a0[2 * j + 1]) << 16);
        s1[j] = (uint32)f2bf(a1[2 * j]) | ((uint32)f2bf(a1[2 * j + 1]) << 16);
    }
    *(uint4*)(dst + (ty + oy) * 128 + tx + ox)     = make_uint4(s0[0], s0[1], s0[2], s0[3]);
    *(uint4*)(dst + (ty + oy + 1) * 128 + tx + ox) = make_uint4(s1[0], s1[1], s1[2], s1[3]);
}

// ---------- Stage E: ifftshift + inverse FFT (conj trick) + residual add ----------
__global__ __launch_bounds__(512) void ifft_add(const ushortt* __restrict__ convRe,
                                                const ushortt* __restrict__ convIm,
                                                const float* __restrict__ x,
                                                float* __restrict__ out) {
    __shared__ float sre[128][129];
    __shared__ float sim[128][129];
    __shared__ float twr[64], twi[64];
    int img = blockIdx.x;
    int tid = threadIdx.x;
    const ushortt* cr = convRe + ((size_t)img << 14);
    const ushortt* ci = convIm + ((size_t)img << 14);
    for (int idx2 = tid; idx2 < 8192; idx2 += 512) {
        int u = idx2 >> 6, vp = idx2 & 63, v = vp * 2;
        int p = (u + 64) & 127, q = (v + 64) & 127;
        uint32 re = *(const uint32*)(cr + p * 128 + q);
        uint32 im = *(const uint32*)(ci + p * 128 + q);
        sre[u][v]     =  bf2f((ushortt)(re & 0xffff));
        sre[u][v + 1] =  bf2f((ushortt)(re >> 16));
        sim[u][v]     = -bf2f((ushortt)(im & 0xffff));
        sim[u][v + 1] = -bf2f((ushortt)(im >> 16));
    }
    if (tid < 64) {
        float s, c;
        sincosf(-PIf * (float)tid / 64.0f, &s, &c);
        twr[tid] = c; twi[tid] = s;
    }
    fft2d_128(sre, sim, twr, twi, tid);

    const float* xi = x + (size_t)img * HW;
    float* oo = out + (size_t)img * HW;
    for (int idx2 = tid; idx2 < 8192; idx2 += 512) {
        int y = idx2 >> 6, xp = (idx2 & 63) * 2;
        int ry = brev7(y);
        float r0 = sre[ry][brev7(xp)]     * (1.0f / 128.0f);
        float r1 = sre[ry][brev7(xp + 1)] * (1.0f / 128.0f);
        float2 xv = *(const float2*)(xi + y * 128 + xp);
        float2 ov; ov.x = r0 + xv.x; ov.y = r1 + xv.y;
        *(float2*)(oo + y * 128 + xp) = ov;
    }
}

extern "C" void kernel_launch(void* const* d_in, const int* in_sizes, int n_in,
                              void* d_out, int out_size, void* d_ws, size_t ws_size,
                              hipStream_t stream) {
    const float* x  = (const float*)d_in[0];
    const float* w1 = (const float*)d_in[1];
    const float* b1 = (const float*)d_in[2];
    const float* w2 = (const float*)d_in[3];
    const float* b2 = (const float*)d_in[4];
    const float* wr = (const float*)d_in[5];

    char* ws = (char*)d_ws;
    // region0 [0,128Mi): xf, later overwritten by mix (gemm output)
    ushortt* xfRe  = (ushortt*)ws;
    ushortt* xfIm  = xfRe + 33554432;
    // region1 [128Mi,256Mi): xfT, later overwritten by conv output
    ushortt* xfTRe = (ushortt*)(ws + 134217728);
    ushortt* xfTIm = xfTRe + 33554432;
    ushortt* mixRe  = xfRe,  *mixIm  = xfIm;    // aliases (xf dead after xpose)
    ushortt* convRe = xfTRe, *convIm = xfTIm;   // aliases (xfT dead after gemm)
    float* magc = (float*)(ws + 268435456);
    float* kern = (float*)(ws + 268435456 + 2048);

    hipMemsetAsync(magc, 0, 392 * sizeof(float), stream);
    fft_fwd<<<2048, 512, 0, stream>>>(x, xfRe, xfIm, magc);
    mlp_kern<<<1, 256, 0, stream>>>(magc, w1, b1, w2, b2, kern);
    xpose<<<dim3(256, 4, 16), 256, 0, stream>>>(xfRe, xfIm, xfTRe, xfTIm);
    gemm_mix<<<dim3(128, 2, 16), 256, 0, stream>>>(xfTRe, xfTIm, wr, mixRe, mixIm);
    conv7<<<dim3(4, 512, 8), 256, 0, stream>>>(mixRe, mixIm, kern, xfRe, xfIm);
    ifft_add<<<2048, 512, 0, stream>>>(xfRe, xfIm, x, (float*)d_out);
}

// Round 3
// 903.992 us; speedup vs baseline: 1.8856x; 1.1647x over previous
//
#include <hip/hip_runtime.h>

#define HW 16384
#define PIf 3.14159265358979323846f
typedef unsigned short ushortt;
typedef unsigned int uint32;
typedef __attribute__((ext_vector_type(8))) short short8;
typedef __attribute__((ext_vector_type(4))) float f32x4;

// ---------- bf16 raw helpers ----------
__device__ __forceinline__ float bf2f(ushortt b) {
    return __uint_as_float(((unsigned)b) << 16);
}
__device__ __forceinline__ ushortt f2bf(float f) {
    unsigned u = __float_as_uint(f);
    u += 0x7fffu + ((u >> 16) & 1u);   // RNE
    return (ushortt)(u >> 16);
}
__device__ __forceinline__ int brev7(int v) { return (int)(__brev((unsigned)v) >> 25); }

// ---------- wave-level 128-pt DIF FFT, 2 complex/lane, shuffle-based ----------
// In: lane l holds a=x[l], b=x[l+64] (natural). Out: a=X[brev7(l)], b=X[brev7(l)+1].
// tw[t] = exp(-i*pi*t/64) in LDS (64 entries).
__device__ __forceinline__ void fft128_wave(float& ar, float& ai, float& br, float& bi,
                                            const float* __restrict__ twr,
                                            const float* __restrict__ twi, int l) {
    // stage 0 (d=64): in-register
    {
        float tr = twr[l], ti = twi[l];
        float sr_ = ar + br, si_ = ai + bi;
        float dr = ar - br, di = ai - bi;
        br = dr * tr - di * ti;
        bi = dr * ti + di * tr;
        ar = sr_; ai = si_;
    }
    #pragma unroll
    for (int s = 1; s <= 6; ++s) {
        const int d = 64 >> s;
        float tr = 1.f, ti = 0.f;
        if (d > 1) {
            int k = (l & (d - 1)) << s;
            tr = twr[k]; ti = twi[k];
        }
        bool up = (l & d) != 0;
        {
            float rr = __shfl_xor(ar, d), ri = __shfl_xor(ai, d);
            float sr_ = ar + rr, si_ = ai + ri;
            float dr = rr - ar, di = ri - ai;
            float mr, mi;
            if (d > 1) { mr = dr * tr - di * ti; mi = dr * ti + di * tr; }
            else       { mr = dr; mi = di; }
            ar = up ? mr : sr_;  ai = up ? mi : si_;
        }
        {
            float rr = __shfl_xor(br, d), ri = __shfl_xor(bi, d);
            float sr_ = br + rr, si_ = bi + ri;
            float dr = rr - br, di = ri - bi;
            float mr, mi;
            if (d > 1) { mr = dr * tr - di * ti; mi = dr * ti + di * tr; }
            else       { mr = dr; mi = di; }
            br = up ? mr : sr_;  bi = up ? mi : si_;
        }
    }
}

// ---------- Stage A: forward FFT + fftshift + central-mag accumulation ----------
__global__ __launch_bounds__(512) void fft_fwd(const float* __restrict__ x,
                                               ushortt* __restrict__ xfRe,
                                               ushortt* __restrict__ xfIm,
                                               float* __restrict__ magc) {
    __shared__ float sre[128][129];
    __shared__ float sim[128][129];
    __shared__ float twr[64], twi[64];
    int img = blockIdx.x;
    int tid = threadIdx.x, l = tid & 63, wv = tid >> 6;
    if (tid < 64) {
        float s, c;
        sincosf(-PIf * (float)tid / 64.0f, &s, &c);
        twr[tid] = c; twi[tid] = s;
    }
    const float* xi = x + (size_t)img * HW;
    __syncthreads();

    // row pass: global -> (shuffle FFT) -> LDS natural order, 1-row prefetch
    float nar = xi[(wv * 16) * 128 + l];
    float nbr = xi[(wv * 16) * 128 + 64 + l];
    for (int r = 0; r < 16; ++r) {
        int row = wv * 16 + r;
        float ar = nar, ai = 0.f, br = nbr, bi = 0.f;
        if (r < 15) {
            nar = xi[(row + 1) * 128 + l];
            nbr = xi[(row + 1) * 128 + 64 + l];
        }
        fft128_wave(ar, ai, br, bi, twr, twi, l);
        int e = brev7(l);
        sre[row][e] = ar;  sre[row][e + 1] = br;
        sim[row][e] = ai;  sim[row][e + 1] = bi;
    }
    __syncthreads();

    // column pass: LDS -> (shuffle FFT) -> LDS natural 2D-frequency order
    for (int r = 0; r < 16; ++r) {
        int c = wv * 16 + r;
        float ar = sre[l][c],      ai = sim[l][c];
        float br = sre[l + 64][c], bi = sim[l + 64][c];
        fft128_wave(ar, ai, br, bi, twr, twi, l);
        int e = brev7(l);
        sre[e][c] = ar;  sre[e + 1][c] = br;
        sim[e][c] = ai;  sim[e + 1][c] = bi;
    }
    __syncthreads();

    // coalesced fftshift'd bf16 write (ortho 1/128)
    uint32* oRe = (uint32*)(xfRe + ((size_t)img << 14));
    uint32* oIm = (uint32*)(xfIm + ((size_t)img << 14));
    for (int idx2 = tid; idx2 < 8192; idx2 += 512) {
        int p = idx2 >> 6, qp = idx2 & 63, q = qp * 2;
        int u  = (p + 64) & 127;
        int v0 = (q + 64) & 127;          // even, pair contiguous
        const float sc = 1.0f / 128.0f;
        uint32 re = (uint32)f2bf(sre[u][v0] * sc) | ((uint32)f2bf(sre[u][v0 + 1] * sc) << 16);
        uint32 im = (uint32)f2bf(sim[u][v0] * sc) | ((uint32)f2bf(sim[u][v0 + 1] * sc) << 16);
        oRe[p * 64 + qp] = re;
        oIm[p * 64 + qp] = im;
    }
    // central 7x7 |xf| accumulation (fp32)
    if (tid < 49) {
        int p = 61 + tid / 7, q = 61 + tid % 7;
        int u = (p + 64) & 127, v = (q + 64) & 127;
        float re = sre[u][v], im = sim[u][v];
        float mag = sqrtf(re * re + im * im) * (1.0f / 128.0f);
        atomicAdd(&magc[(img >> 8) * 49 + tid], mag);
    }
}

// ---------- Stage B: tiny MLP + anisotropic kernel build ----------
__global__ __launch_bounds__(256) void mlp_kern(const float* __restrict__ magc,
                                                const float* __restrict__ w1,
                                                const float* __restrict__ b1,
                                                const float* __restrict__ w2,
                                                const float* __restrict__ b2,
                                                float* __restrict__ kern) {
    __shared__ float hid[8][32];
    __shared__ float par[8][3];
    __shared__ float kun[8][49];
    __shared__ float ksum[8];
    int tid = threadIdx.x;
    {
        int b = tid >> 5, n = tid & 31;
        float acc = b1[n];
        for (int i = 0; i < 49; ++i)
            acc = fmaf(magc[b * 49 + i] * (1.0f / 256.0f), w1[i * 32 + n], acc);
        hid[b][n] = fmaxf(acc, 0.f);
    }
    __syncthreads();
    if (tid < 24) {
        int b = tid / 3, j = tid % 3;
        float acc = b2[j];
        for (int n = 0; n < 32; ++n) acc = fmaf(hid[b][n], w2[n * 3 + j], acc);
        par[b][j] = acc;
    }
    __syncthreads();
    for (int idx = tid; idx < 392; idx += 256) {
        int b = idx / 49, ij = idx % 49;
        int i = ij / 7, j2 = ij % 7;
        float p0 = par[b][0], p1 = par[b][1], p2 = par[b][2];
        float theta = atan2f(p0, p1) * 0.5f + PIf * 0.5f;
        float lam1 = expf(p2);
        float lam2 = 1.0f / (lam1 + 1e-8f);
        float yy = (float)(i - 3), xx = (float)(j2 - 3);
        float ct, st;
        sincosf(theta, &st, &ct);
        float xr =  xx * ct + yy * st;
        float yr = -xx * st + yy * ct;
        kun[b][ij] = expf(-(xr * xr / (2.f * lam1 * lam1) + yr * yr / (2.f * lam2 * lam2)));
    }
    __syncthreads();
    if (tid < 8) {
        float s = 0.f;
        for (int t = 0; t < 49; ++t) s += kun[tid][t];
        ksum[tid] = s + 1e-8f;
    }
    __syncthreads();
    for (int idx = tid; idx < 392; idx += 256)
        kern[idx] = kun[idx / 49][idx % 49] / ksum[idx / 49];
}

// ---------- Stage C0: transpose xf[c][pix] -> xfT[pix][c] ----------
__global__ __launch_bounds__(256) void xpose(const ushortt* __restrict__ xfRe,
                                             const ushortt* __restrict__ xfIm,
                                             ushortt* __restrict__ xfTRe,
                                             ushortt* __restrict__ xfTIm) {
    __shared__ ushortt T[64 * 65];
    int b = blockIdx.z >> 1, arr = blockIdx.z & 1;
    const ushortt* src = (arr ? xfIm : xfRe) + (size_t)b * (256 * HW);
    ushortt* dst = (arr ? xfTIm : xfTRe) + (size_t)b * (HW * 256);
    int pixBase = blockIdx.x * 64, cBase = blockIdx.y * 64;
    int tid = threadIdx.x;
    #pragma unroll
    for (int i = 0; i < 16; ++i) {
        int idx = tid + i * 256; int c = idx >> 6, p = idx & 63;
        T[c * 65 + p] = src[(size_t)(cBase + c) * HW + pixBase + p];
    }
    __syncthreads();
    #pragma unroll
    for (int i = 0; i < 16; ++i) {
        int idx = tid + i * 256; int p = idx >> 6, c = idx & 63;
        dst[(size_t)(pixBase + p) * 256 + cBase + c] = T[c * 65 + p];
    }
}

// ---------- Stage C: channel mixing via bf16 MFMA ----------
__global__ __launch_bounds__(256) void gemm_mix(const ushortt* __restrict__ xfTRe,
                                                const ushortt* __restrict__ xfTIm,
                                                const float* __restrict__ wr,
                                                ushortt* __restrict__ mixRe,
                                                ushortt* __restrict__ mixIm) {
    __shared__ ushortt lA[2][5120];   // [o=128][k=32] stride 40 ushorts
    __shared__ ushortt lB[2][5120];   // [pix=128][k=32] stride 40
    int tid = threadIdx.x;
    int lane = tid & 63, wave = tid >> 6;
    int wm = wave >> 1, wn = wave & 1;
    int l15 = lane & 15, q4 = lane >> 4;
    int b = blockIdx.z >> 1, part = blockIdx.z & 1;
    const ushortt* X = (part ? xfTIm : xfTRe) + (size_t)b * (HW * 256)
                       + (size_t)blockIdx.x * (128 * 256);
    ushortt* Dst = (part ? mixIm : mixRe) + (size_t)b * (256 * HW)
                   + (size_t)(blockIdx.y * 128) * HW + blockIdx.x * 128;
    const float* W = wr + (blockIdx.y * 128) * 256;

    int srow = tid >> 1, shalf = tid & 1;
    const float*   wRow = W + srow * 256 + shalf * 16;
    const ushortt* xRow = X + srow * 256 + shalf * 16;
    int ldsOff = srow * 40 + shalf * 16;

    float4 wreg[4];
    uint4  xreg[2];
    #pragma unroll
    for (int i = 0; i < 4; ++i) wreg[i] = *(const float4*)(wRow + i * 4);
    #pragma unroll
    for (int i = 0; i < 2; ++i) xreg[i] = *(const uint4*)(xRow + i * 8);

    f32x4 acc[4][4];
    #pragma unroll
    for (int i = 0; i < 4; ++i)
        #pragma unroll
        for (int j = 0; j < 4; ++j)
            #pragma unroll
            for (int k = 0; k < 4; ++k) acc[i][j][k] = 0.f;

    int abase = (wm * 64 + l15) * 40 + q4 * 8;
    int bbase = (wn * 64 + l15) * 40 + q4 * 8;

    for (int kb = 0; kb < 8; ++kb) {
        int bufc = kb & 1;
        float ff[16] = {wreg[0].x, wreg[0].y, wreg[0].z, wreg[0].w,
                        wreg[1].x, wreg[1].y, wreg[1].z, wreg[1].w,
                        wreg[2].x, wreg[2].y, wreg[2].z, wreg[2].w,
                        wreg[3].x, wreg[3].y, wreg[3].z, wreg[3].w};
        uint32 p[8];
        #pragma unroll
        for (int j = 0; j < 8; ++j)
            p[j] = (uint32)f2bf(ff[2 * j]) | ((uint32)f2bf(ff[2 * j + 1]) << 16);
        *(uint4*)&lA[bufc][ldsOff]     = make_uint4(p[0], p[1], p[2], p[3]);
        *(uint4*)&lA[bufc][ldsOff + 8] = make_uint4(p[4], p[5], p[6], p[7]);
        *(uint4*)&lB[bufc][ldsOff]     = xreg[0];
        *(uint4*)&lB[bufc][ldsOff + 8] = xreg[1];
        __syncthreads();
        if (kb < 7) {
            const float*   wN = wRow + (kb + 1) * 32;
            const ushortt* xN = xRow + (kb + 1) * 32;
            #pragma unroll
            for (int i = 0; i < 4; ++i) wreg[i] = *(const float4*)(wN + i * 4);
            #pragma unroll
            for (int i = 0; i < 2; ++i) xreg[i] = *(const uint4*)(xN + i * 8);
        }
        short8 af[4], bf[4];
        #pragma unroll
        for (int f = 0; f < 4; ++f) af[f] = *(const short8*)&lA[bufc][abase + f * 640];
        #pragma unroll
        for (int f = 0; f < 4; ++f) bf[f] = *(const short8*)&lB[bufc][bbase + f * 640];
        #pragma unroll
        for (int fi = 0; fi < 4; ++fi)
            #pragma unroll
            for (int fj = 0; fj < 4; ++fj)
                acc[fi][fj] = __builtin_amdgcn_mfma_f32_16x16x32_bf16(
                    af[fi], bf[fj], acc[fi][fj], 0, 0, 0);
    }
    #pragma unroll
    for (int fi = 0; fi < 4; ++fi) {
        #pragma unroll
        for (int r = 0; r < 4; ++r) {
            int o_l = wm * 64 + fi * 16 + q4 * 4 + r;
            ushortt* dp = Dst + (size_t)o_l * HW + wn * 64 + l15;
            #pragma unroll
            for (int fj = 0; fj < 4; ++fj)
                dp[fj * 16] = f2bf(acc[fi][fj][r]);
        }
    }
}

// ---------- Stage D: 7x7 zero-padded conv, register-blocked 2x8/thread ----------
__global__ __launch_bounds__(256) void conv7(const ushortt* __restrict__ mixRe,
                                             const ushortt* __restrict__ mixIm,
                                             const float* __restrict__ kern,
                                             ushortt* __restrict__ outRe,
                                             ushortt* __restrict__ outIm) {
    __shared__ float tile[70 * 73];
    int b = blockIdx.z;
    int plane = blockIdx.y;
    int part = plane >> 8;
    size_t pbase = ((size_t)(b * 256 + (plane & 255))) << 14;
    const ushortt* src = (part ? mixIm : mixRe) + pbase;
    ushortt* dst = (part ? outIm : outRe) + pbase;
    int ty = (blockIdx.x >> 1) * 64, tx = (blockIdx.x & 1) * 64;
    int tid = threadIdx.x;
    float kv[49];
    #pragma unroll
    for (int i = 0; i < 49; ++i) kv[i] = kern[b * 49 + i];
    for (int idx = tid; idx < 4900; idx += 256) {
        int i = idx / 70, j = idx - i * 70;
        int r = ty + i - 3, c = tx + j - 3;
        float v = 0.f;
        if ((unsigned)r < 128u && (unsigned)c < 128u) v = bf2f(src[r * 128 + c]);
        tile[i * 73 + j] = v;
    }
    __syncthreads();
    int ox = (tid & 7) * 8, oy = (tid >> 3) * 2;
    float a0[8], a1[8];
    #pragma unroll
    for (int j = 0; j < 8; ++j) { a0[j] = 0.f; a1[j] = 0.f; }
    #pragma unroll
    for (int dyy = 0; dyy < 8; ++dyy) {
        float row[14];
        #pragma unroll
        for (int j = 0; j < 14; ++j) row[j] = tile[(oy + dyy) * 73 + ox + j];
        if (dyy < 7) {
            #pragma unroll
            for (int dx = 0; dx < 7; ++dx) {
                float k = kv[dyy * 7 + dx];
                #pragma unroll
                for (int j = 0; j < 8; ++j) a0[j] = fmaf(row[dx + j], k, a0[j]);
            }
        }
        if (dyy >= 1) {
            #pragma unroll
            for (int dx = 0; dx < 7; ++dx) {
                float k = kv[(dyy - 1) * 7 + dx];
                #pragma unroll
                for (int j = 0; j < 8; ++j) a1[j] = fmaf(row[dx + j], k, a1[j]);
            }
        }
    }
    uint32 s0[4], s1[4];
    #pragma unroll
    for (int j = 0; j < 4; ++j) {
        s0[j] = (uint32)f2bf(a0[2 * j]) | ((uint32)f2bf(a0[2 * j + 1]) << 16);
        s1[j] = (uint32)f2bf(a1[2 * j]) | ((uint32)f2bf(a1[2 * j + 1]) << 16);
    }
    *(uint4*)(dst + (ty + oy) * 128 + tx + ox)     = make_uint4(s0[0], s0[1], s0[2], s0[3]);
    *(uint4*)(dst + (ty + oy + 1) * 128 + tx + ox) = make_uint4(s1[0], s1[1], s1[2], s1[3]);
}

// ---------- Stage E: ifftshift + inverse FFT (conj trick) + residual add ----------
__global__ __launch_bounds__(512) void ifft_add(const ushortt* __restrict__ convRe,
                                                const ushortt* __restrict__ convIm,
                                                const float* __restrict__ x,
                                                float* __restrict__ out) {
    __shared__ float sre[128][129];
    __shared__ float sim[128][129];
    __shared__ float twr[64], twi[64];
    int img = blockIdx.x;
    int tid = threadIdx.x, l = tid & 63, wv = tid >> 6;
    if (tid < 64) {
        float s, c;
        sincosf(-PIf * (float)tid / 64.0f, &s, &c);
        twr[tid] = c; twi[tid] = s;
    }
    const ushortt* cr = convRe + ((size_t)img << 14);
    const ushortt* ci = convIm + ((size_t)img << 14);
    __syncthreads();

    // row pass: ifftshift gather from global (conj), shuffle FFT, LDS natural, 1-row prefetch
    {
        int p0 = ((wv * 16) + 64) & 127;
        float nar = bf2f(cr[p0 * 128 + 64 + l]), nai = bf2f(ci[p0 * 128 + 64 + l]);
        float nbr = bf2f(cr[p0 * 128 + l]),      nbi = bf2f(ci[p0 * 128 + l]);
        for (int r = 0; r < 16; ++r) {
            int u = wv * 16 + r;
            float ar = nar, ai = -nai, br = nbr, bi = -nbi;
            if (r < 15) {
                int p = ((u + 1) + 64) & 127;
                nar = bf2f(cr[p * 128 + 64 + l]); nai = bf2f(ci[p * 128 + 64 + l]);
                nbr = bf2f(cr[p * 128 + l]);      nbi = bf2f(ci[p * 128 + l]);
            }
            fft128_wave(ar, ai, br, bi, twr, twi, l);
            int e = brev7(l);
            sre[u][e] = ar;  sre[u][e + 1] = br;
            sim[u][e] = ai;  sim[u][e + 1] = bi;
        }
    }
    __syncthreads();

    // column pass; only the real part is needed for the output
    for (int r = 0; r < 16; ++r) {
        int c = wv * 16 + r;
        float ar = sre[l][c],      ai = sim[l][c];
        float br = sre[l + 64][c], bi = sim[l + 64][c];
        fft128_wave(ar, ai, br, bi, twr, twi, l);
        int e = brev7(l);
        sre[e][c] = ar;  sre[e + 1][c] = br;
    }
    __syncthreads();

    const float* xi = x + (size_t)img * HW;
    float* oo = out + (size_t)img * HW;
    for (int idx2 = tid; idx2 < 8192; idx2 += 512) {
        int y = idx2 >> 6, xp = (idx2 & 63) * 2;
        float r0 = sre[y][xp]     * (1.0f / 128.0f);
        float r1 = sre[y][xp + 1] * (1.0f / 128.0f);
        float2 xv = *(const float2*)(xi + y * 128 + xp);
        float2 ov; ov.x = r0 + xv.x; ov.y = r1 + xv.y;
        *(float2*)(oo + y * 128 + xp) = ov;
    }
}

extern "C" void kernel_launch(void* const* d_in, const int* in_sizes, int n_in,
                              void* d_out, int out_size, void* d_ws, size_t ws_size,
                              hipStream_t stream) {
    const float* x  = (const float*)d_in[0];
    const float* w1 = (const float*)d_in[1];
    const float* b1 = (const float*)d_in[2];
    const float* w2 = (const float*)d_in[3];
    const float* b2 = (const float*)d_in[4];
    const float* wr = (const float*)d_in[5];

    char* ws = (char*)d_ws;
    ushortt* xfRe  = (ushortt*)ws;
    ushortt* xfIm  = xfRe + 33554432;
    ushortt* xfTRe = (ushortt*)(ws + 134217728);
    ushortt* xfTIm = xfTRe + 33554432;
    ushortt* mixRe  = xfRe,  *mixIm  = xfIm;    // aliases (xf dead after xpose)
    ushortt* convRe = xfTRe, *convIm = xfTIm;   // aliases (xfT dead after gemm)
    float* magc = (float*)(ws + 268435456);
    float* kern = (float*)(ws + 268435456 + 2048);

    hipMemsetAsync(magc, 0, 392 * sizeof(float), stream);
    fft_fwd<<<2048, 512, 0, stream>>>(x, xfRe, xfIm, magc);
    mlp_kern<<<1, 256, 0, stream>>>(magc, w1, b1, w2, b2, kern);
    xpose<<<dim3(256, 4, 16), 256, 0, stream>>>(xfRe, xfIm, xfTRe, xfTIm);
    gemm_mix<<<dim3(128, 2, 16), 256, 0, stream>>>(xfTRe, xfTIm, wr, mixRe, mixIm);
    conv7<<<dim3(4, 512, 8), 256, 0, stream>>>(mixRe, mixIm, kern, xfRe, xfIm);
    ifft_add<<<2048, 512, 0, stream>>>(xfRe, xfIm, x, (float*)d_out);
}